// Round 3
// baseline (488.740 us; speedup 1.0000x reference)
//
#include <hip/hip_runtime.h>
#include <cfloat>

#define HH 64
#define WW 64
#define NKEYS 17
#define CCH 32
#define BG_W 10.0f

typedef float vf4 __attribute__((ext_vector_type(4)));

__device__ inline void wave_argmin(float &v, int &i) {
    #pragma unroll
    for (int off = 32; off > 0; off >>= 1) {
        float ov = __shfl_down(v, off, 64);
        int   oi = __shfl_down(i, off, 64);
        if (ov < v || (ov == v && oi < i)) { v = ov; i = oi; }
    }
}

__device__ inline unsigned long long pack_vi(float v, int i) {
    return ((unsigned long long)__float_as_uint(v) << 32) | (unsigned int)i;
}

// ---------------- Kernel A: weighted distance map + coarse argmin ----------------
__global__ __launch_bounds__(256) void ee_coarse(
    const float* __restrict__ kq,      // (B, C, 64, 64)
    const float* __restrict__ mkeys,   // (B, N, C)
    const int*   __restrict__ mjoints, // (B, N, 2)
    float* __restrict__ out_valid,     // (B*N) as float
    float* __restrict__ out_keys,      // (B*N, C)
    float* __restrict__ ws_wd,         // (B*N, 4096)
    unsigned long long* __restrict__ ws_fine, // (B*N)
    int Bsz)
{
    // XCD swizzle: co-locate all 17 n-blocks of one b on the same XCD (blockIdx%8 heuristic)
    int bn;
    if ((Bsz & 7) == 0) {
        const int xcd  = blockIdx.x & 7;
        const int slot = blockIdx.x >> 3;
        const int b    = xcd + 8 * (slot / NKEYS);
        const int n    = slot % NKEYS;
        bn = b * NKEYS + n;
    } else {
        bn = blockIdx.x;
    }
    const int b   = bn / NKEYS;
    const int tid = threadIdx.x;

    __shared__ float s_mk[CCH];
    __shared__ float s_rv[4];
    __shared__ int   s_ri[4];

    if (tid < CCH) s_mk[tid] = mkeys[bn * CCH + tid];
    __syncthreads();

    float k2 = 0.0f;
    bool  nz = false;
    #pragma unroll
    for (int c = 0; c < CCH; c++) {
        float v = s_mk[c];
        k2 += v * v;
        nz = nz || (v != 0.0f);
    }

    const int kpx = mjoints[bn * 2 + 0];
    const int kpy = mjoints[bn * 2 + 1];
    const int m_left  = max(kpx, 1);
    const int m_right = max(WW - 1 - kpx, 1);
    const int m_up    = max(kpy, 1);
    const int m_down  = max(HH - 1 - kpy, 1);

    const float4* kq4 = (const float4*)(kq + (size_t)b * CCH * HH * WW);
    float4* wd4 = (float4*)(ws_wd + (size_t)bn * (HH * WW));

    float bestv = FLT_MAX;
    int   besti = 0;

    for (int j = 0; j < 4; j++) {
        const int chunk = tid + 256 * j;   // float4 chunk id, 0..1023
        float4 dot = make_float4(0.f, 0.f, 0.f, 0.f);
        float4 q2  = make_float4(0.f, 0.f, 0.f, 0.f);
        #pragma unroll
        for (int c = 0; c < CCH; c++) {
            float4 v = kq4[c * 1024 + chunk];
            float  m = s_mk[c];
            dot.x += v.x * m;  dot.y += v.y * m;
            dot.z += v.z * m;  dot.w += v.w * m;
            q2.x  += v.x * v.x; q2.y += v.y * v.y;
            q2.z  += v.z * v.z; q2.w += v.w * v.w;
        }
        float dots[4] = {dot.x, dot.y, dot.z, dot.w};
        float q2s[4]  = {q2.x,  q2.y,  q2.z,  q2.w};
        float4 wd;
        float* wdp = (float*)&wd;
        const int p0 = chunk * 4;
        #pragma unroll
        for (int k = 0; k < 4; k++) {
            const int p  = p0 + k;
            const int px = p & (WW - 1);
            const int py = p >> 6;
            float d2   = (q2s[k] + k2) - 2.0f * dots[k];
            float dist = sqrtf(fmaxf(d2, 0.0f));
            float wgt  = BG_W;
            #pragma unroll
            for (int m = 1; m <= 15; m++) {
                int xl = max(kpx - m, 0);
                int xr = min(kpx + m, WW - 1);
                int yu = max(kpy - m, 0);
                int yd = min(kpy + m, HH - 1);
                bool col = (((px == xl) && (m <= m_left)) || ((px == xr) && (m <= m_right)))
                           && (py >= yu) && (py <= yd);
                bool row = (((py == yu) && (m <= m_up)) || ((py == yd) && (m <= m_down)))
                           && (px >= xl) && (px <= xr);
                if (col || row) wgt = 0.5f + 0.25f * (float)m;
            }
            float wv = dist * wgt;
            wdp[k] = wv;
            if (wv < bestv) { bestv = wv; besti = p; }  // p ascending per-thread -> first occurrence
        }
        wd4[chunk] = wd;
    }

    // block argmin (lexicographic: value, then lower index)
    wave_argmin(bestv, besti);
    if ((tid & 63) == 0) { s_rv[tid >> 6] = bestv; s_ri[tid >> 6] = besti; }
    __syncthreads();
    if (tid == 0) {
        float v = s_rv[0]; int i0 = s_ri[0];
        for (int w2 = 1; w2 < 4; w2++) {
            float ov = s_rv[w2]; int oi = s_ri[w2];
            if (ov < v || (ov == v && oi < i0)) { v = ov; i0 = oi; }
        }
        s_rv[0] = v; s_ri[0] = i0;
        ws_fine[bn] = ~0ULL;   // init for kernel B's atomicMin
    }
    __syncthreads();
    const float min_d = s_rv[0];
    const int   cbest = s_ri[0];
    const bool  valid = nz && ((int)floorf(min_d) <= 5);

    if (tid < CCH) {
        float o = valid ? kq[(size_t)(b * CCH + tid) * (HH * WW) + cbest] : s_mk[tid];
        out_keys[bn * CCH + tid] = o;
    }
    if (tid == 0) out_valid[bn] = valid ? 1.0f : 0.0f;
}

// ---------------- Kernel B: 4x bilinear upsample + fine argmin ----------------
// 4 blocks per (b,n); block q handles coarse rows [16q,16q+16) -> output rows [64q,64q+64).
// Thread t: x-group g = t&63 (4 consecutive output cols), row-group rg = t>>6 (4 coarse rows).
__global__ __launch_bounds__(256) void ee_upsample(
    const float* __restrict__ ws_wd,
    unsigned long long* __restrict__ ws_fine,
    float* __restrict__ out_x4,
    int Bsz)
{
    int bn, q;
    if ((Bsz & 7) == 0) {
        const int xcd   = blockIdx.x & 7;
        const int slot  = blockIdx.x >> 3;    // 0..(Bsz*NKEYS*4/8 - 1)
        q = slot & 3;
        const int slot2 = slot >> 2;          // 0..(Bsz*NKEYS/8 - 1)
        const int b     = xcd + 8 * (slot2 / NKEYS);
        const int n     = slot2 % NKEYS;
        bn = b * NKEYS + n;
    } else {
        bn = blockIdx.x >> 2;
        q  = blockIdx.x & 3;
    }
    const int tid = threadIdx.x;
    const int g   = tid & 63;
    const int rg  = tid >> 6;

    __shared__ float s_rows[18][WW];   // coarse rows 16q-1 .. 16q+16 (clamped)
    __shared__ float s_rv[4];
    __shared__ int   s_ri[4];

    const float* wd = ws_wd + (size_t)bn * (HH * WW);
    for (int t = tid; t < 18 * WW; t += 256) {
        const int cr  = t >> 6;          // 0..17
        const int col = t & 63;
        const int gjy = min(max(16 * q + cr - 1, 0), HH - 1);
        s_rows[cr][col] = wd[gjy * WW + col];
    }
    __syncthreads();

    const int gl = max(g - 1, 0);
    const int gr = min(g + 1, WW - 1);
    const bool xe0 = (g == 0);
    const bool xe1 = (g == WW - 1);

    // x-lerp of coarse local row lr (global jy = 16q+lr); s_rows index = lr+1
    auto Hrow = [&](int lr, float h[4]) {
        const float* r = s_rows[lr + 1];
        const float A = r[gl], Bv = r[g], Cv = r[gr];
        h[0] = xe0 ? Bv : 0.375f * A  + 0.625f * Bv;
        h[1] = xe0 ? Bv : 0.125f * A  + 0.875f * Bv;
        h[2] = xe1 ? Bv : 0.875f * Bv + 0.125f * Cv;
        h[3] = xe1 ? Bv : 0.625f * Bv + 0.375f * Cv;
    };

    float hp[4], hc[4], hn[4];
    const int lr0 = 4 * rg;
    Hrow(lr0 - 1, hp);
    Hrow(lr0,     hc);

    float fbv = FLT_MAX;
    int   fbi = 0;
    float* xout = out_x4 + (size_t)bn * (256 * 256) + 4 * g;

    for (int lr = lr0; lr < lr0 + 4; lr++) {
        Hrow(lr + 1, hn);
        const int jy = 16 * q + lr;
        const bool y0 = (jy == 0);
        const bool y1 = (jy == HH - 1);
        float v0[4], v1[4], v2[4], v3[4];
        #pragma unroll
        for (int c = 0; c < 4; c++) {
            v0[c] = y0 ? hc[c] : 0.375f * hp[c] + 0.625f * hc[c];
            v1[c] = y0 ? hc[c] : 0.125f * hp[c] + 0.875f * hc[c];
            v2[c] = y1 ? hc[c] : 0.875f * hc[c] + 0.125f * hn[c];
            v3[c] = y1 ? hc[c] : 0.625f * hc[c] + 0.375f * hn[c];
        }
        const int r0 = 4 * jy;
        vf4 sv0 = {v0[0], v0[1], v0[2], v0[3]};
        vf4 sv1 = {v1[0], v1[1], v1[2], v1[3]};
        vf4 sv2 = {v2[0], v2[1], v2[2], v2[3]};
        vf4 sv3 = {v3[0], v3[1], v3[2], v3[3]};
        __builtin_nontemporal_store(sv0, (vf4*)(xout + (size_t)(r0 + 0) * 256));
        __builtin_nontemporal_store(sv1, (vf4*)(xout + (size_t)(r0 + 1) * 256));
        __builtin_nontemporal_store(sv2, (vf4*)(xout + (size_t)(r0 + 2) * 256));
        __builtin_nontemporal_store(sv3, (vf4*)(xout + (size_t)(r0 + 3) * 256));
        // fine argmin candidates, ascending flat index within this thread
        #pragma unroll
        for (int c = 0; c < 4; c++) {
            int i0 = (r0 + 0) * 256 + 4 * g + c;
            if (v0[c] < fbv) { fbv = v0[c]; fbi = i0; }
        }
        #pragma unroll
        for (int c = 0; c < 4; c++) {
            int i0 = (r0 + 1) * 256 + 4 * g + c;
            if (v1[c] < fbv) { fbv = v1[c]; fbi = i0; }
        }
        #pragma unroll
        for (int c = 0; c < 4; c++) {
            int i0 = (r0 + 2) * 256 + 4 * g + c;
            if (v2[c] < fbv) { fbv = v2[c]; fbi = i0; }
        }
        #pragma unroll
        for (int c = 0; c < 4; c++) {
            int i0 = (r0 + 3) * 256 + 4 * g + c;
            if (v3[c] < fbv) { fbv = v3[c]; fbi = i0; }
        }
        #pragma unroll
        for (int c = 0; c < 4; c++) { hp[c] = hc[c]; hc[c] = hn[c]; }
    }

    wave_argmin(fbv, fbi);
    if ((tid & 63) == 0) { s_rv[tid >> 6] = fbv; s_ri[tid >> 6] = fbi; }
    __syncthreads();
    if (tid == 0) {
        float v = s_rv[0]; int i0 = s_ri[0];
        for (int w2 = 1; w2 < 4; w2++) {
            float ov = s_rv[w2]; int oi = s_ri[w2];
            if (ov < v || (ov == v && oi < i0)) { v = ov; i0 = oi; }
        }
        atomicMin(&ws_fine[bn], pack_vi(v, i0));
    }
}

// ---------------- Kernel C: finalize joints ----------------
__global__ void ee_final(const unsigned long long* __restrict__ ws_fine,
                         const float* __restrict__ out_valid,
                         float* __restrict__ out_joints, int BN)
{
    const int bn = blockIdx.x * 256 + threadIdx.x;
    if (bn >= BN) return;
    const bool valid = out_valid[bn] != 0.0f;
    const unsigned long long p = ws_fine[bn];
    const int idx = (int)(unsigned int)(p & 0xFFFFFFFFu);
    out_joints[2 * bn + 0] = valid ? (float)(idx >> 8)  : -1.0f;
    out_joints[2 * bn + 1] = valid ? (float)(idx & 255) : -1.0f;
}

extern "C" void kernel_launch(void* const* d_in, const int* in_sizes, int n_in,
                              void* d_out, int out_size, void* d_ws, size_t ws_size,
                              hipStream_t stream) {
    const float* kq = (const float*)d_in[0];
    const float* mk = (const float*)d_in[1];
    const int*   mj = (const int*)d_in[2];

    const int Bsz = in_sizes[1] / (NKEYS * CCH);   // 64
    const int BN  = Bsz * NKEYS;                   // 1088

    float* out_f    = (float*)d_out;
    float* o_joints = out_f;                  // BN*2
    float* o_valid  = o_joints + BN * 2;      // BN
    float* o_keys   = o_valid + BN;           // BN*C
    float* o_x4     = o_keys + BN * CCH;      // BN*256*256

    float* ws_wd = (float*)d_ws;                                  // BN*4096 floats
    unsigned long long* ws_fine =
        (unsigned long long*)((char*)d_ws + (size_t)BN * HH * WW * sizeof(float));

    ee_coarse  <<<dim3(BN),            dim3(256), 0, stream>>>(kq, mk, mj, o_valid, o_keys, ws_wd, ws_fine, Bsz);
    ee_upsample<<<dim3(BN * 4),        dim3(256), 0, stream>>>(ws_wd, ws_fine, o_x4, Bsz);
    ee_final   <<<dim3((BN + 255)/256),dim3(256), 0, stream>>>(ws_fine, o_valid, o_joints, BN);
}